// Round 4
// baseline (810.107 us; speedup 1.0000x reference)
//
#include <hip/hip_runtime.h>

// Problem constants (from reference): 16 clouds x 4096 pts, sample 1024, D=512
#define N_PER   4096
#define M_SAMP  1024
#define B_CL    16
#define D_FEAT  512
#define TPB     256
#define NWAVE   (TPB / 64)      // 4 waves
#define PPT     (N_PER / TPB)   // 16 points per thread
#define NPAIR   (PPT / 2)       // 8 packed pairs per thread

typedef float v2f __attribute__((ext_vector_type(2)));

// ---------------------------------------------------------------------------
// u32 DPP max combine (value-only wave reduce). Lanes not supplied by the
// pattern combine with themselves (old == own value -> no-op).
// ---------------------------------------------------------------------------
template <int CTRL>
__device__ __forceinline__ unsigned dpp_maxu(unsigned v) {
    unsigned o = (unsigned)__builtin_amdgcn_update_dpp((int)v, (int)v, CTRL, 0xF, 0xF, false);
    return (o > v) ? o : v;
}

// ---------------------------------------------------------------------------
// FPS: one workgroup per cloud, 256 threads, 1 wave/SIMD (measured-best:
// R1 spin +29%, R3 2-waves/SIMD +7% -- both reverted).
//
// This round: kill the SECOND post-barrier LDS round. Previously the serial
// chain per step was: barrier -> read 4 keys (~130cy) -> merge -> dependent
// spos[widx] read (~130cy). Now each wave ships its winner's COORDS with its
// key: a divergent spos[base+bj] read issued early (hides under the DPP
// chain), 3 readlanes from the winner lane, lane0 writes key(b64)+coords
// (b128). Post-barrier: read 4 keys + 4 coord packets in one pipelined burst,
// merge keys and cndmask-select coords (keys unique -> select exact).
//
// Exactness: distance math contract(off) same op order; value-only max3
// tracking + descending equality scan (min j); u32 DPP value reduce;
// ballot->ctz winner lane (lane order == idx order); cross-wave u64 key
// (dist bits << 32 | (4095-idx)) -> max dist, tie -> min idx. Identical
// semantics to the verified 549us kernel.
// ---------------------------------------------------------------------------
__global__ __launch_bounds__(TPB)
__attribute__((amdgpu_waves_per_eu(1, 1)))
void fps_kernel(const float* __restrict__ pos, int* __restrict__ sidx) {
    __shared__ float4             spos[N_PER];       // 64 KiB coord table
    __shared__ unsigned long long swk[2][NWAVE];     // double-buffered wave keys
    __shared__ float4             swc[2][NWAVE];     // winner coords per wave
    __shared__ int                sloc[M_SAMP];      // sampled local indices

    const int cloud = blockIdx.x;
    const int tid   = threadIdx.x;
    const float* posb = pos + (size_t)cloud * N_PER * 3;

    // preload my 16 points (12 aligned float4 from global), pack into v2f regs,
    // and stage the same points into spos (one-time)
    v2f px2[NPAIR], py2[NPAIR], pz2[NPAIR], dist2[NPAIR];
    const int base = tid * PPT;
    {
        float f[48];
        const float4* posb4 = (const float4*)posb + tid * 12;
#pragma unroll
        for (int v = 0; v < 12; ++v) {
            float4 t = posb4[v];
            f[4 * v + 0] = t.x; f[4 * v + 1] = t.y;
            f[4 * v + 2] = t.z; f[4 * v + 3] = t.w;
        }
#pragma unroll
        for (int p = 0; p < NPAIR; ++p) {
            px2[p] = (v2f){f[6 * p + 0], f[6 * p + 3]};
            py2[p] = (v2f){f[6 * p + 1], f[6 * p + 4]};
            pz2[p] = (v2f){f[6 * p + 2], f[6 * p + 5]};
            dist2[p] = (v2f){1e30f, 1e30f};
        }
#pragma unroll
        for (int j = 0; j < PPT; ++j)
            spos[base + j] = make_float4(f[3 * j], f[3 * j + 1], f[3 * j + 2], 0.0f);
    }

    float lx = posb[0], ly = posb[1], lz = posb[2];   // start point = local 0
    if (tid == 0) sloc[0] = 0;

    const int wave = tid >> 6;
    const int lane = tid & 63;
    __syncthreads();   // spos visible

    for (int s = 1; s < M_SAMP; ++s) {
        float bv = -1.0f;     // all dist >= 0, so always beaten
        v2f lxv = {lx, lx}, lyv = {ly, ly}, lzv = {lz, lz};
#pragma unroll
        for (int p = 0; p < NPAIR; ++p) {
#pragma clang fp contract(off)
            v2f dx = px2[p] - lxv;
            v2f dy = py2[p] - lyv;
            v2f dz = pz2[p] - lzv;
            v2f d2 = dx * dx + dy * dy + dz * dz;          // contract off: exact jnp order
            v2f dn = __builtin_elementwise_min(dist2[p], d2);
            dist2[p] = dn;
            // value-only running max: one v_max3_f32 per pair
            asm("v_max3_f32 %0, %1, %2, %3" : "=v"(bv) : "v"(bv), "v"(dn.x), "v"(dn.y));
        }

        // first-occurrence j among my 16 slots: descending overwrite -> min j
        int bj = 0;
#pragma unroll
        for (int j = PPT - 1; j >= 0; --j) {
            float dj = (j & 1) ? dist2[j >> 1].y : dist2[j >> 1].x;
            bj = (dj == bv) ? j : bj;
        }

        // candidate coords, issued EARLY so the ~130cy LDS latency hides
        // under the DPP chain below (divergent read, latency off the chain)
        float4 cand = spos[base + bj];

        // wave64 value max via u32 DPP (bv >= 0 -> float bits monotone)
        unsigned khi = __float_as_uint(bv);
        unsigned r = khi;
        r = dpp_maxu<0xB1>(r);     // quad_perm xor1
        r = dpp_maxu<0x4E>(r);     // quad_perm xor2
        r = dpp_maxu<0x141>(r);    // row_half_mirror
        r = dpp_maxu<0x140>(r);    // row_mirror
        r = dpp_maxu<0x142>(r);    // row_bcast15
        r = dpp_maxu<0x143>(r);    // row_bcast31  -> lane63 holds wave max

        unsigned smax = (unsigned)__builtin_amdgcn_readlane((int)r, 63);
        unsigned long long mask = __ballot(khi == smax);   // nonzero by construction
        int sl = __builtin_ctzll(mask);                    // first lane == lowest idx
        int widx_w = __builtin_amdgcn_readlane(base + bj, sl);  // wave winner idx
        float cx = __uint_as_float((unsigned)__builtin_amdgcn_readlane(__float_as_int(cand.x), sl));
        float cy = __uint_as_float((unsigned)__builtin_amdgcn_readlane(__float_as_int(cand.y), sl));
        float cz = __uint_as_float((unsigned)__builtin_amdgcn_readlane(__float_as_int(cand.z), sl));

        const int buf = s & 1;
        if (lane == 0) {
            swk[buf][wave] = ((unsigned long long)smax << 32) |
                             (unsigned)(N_PER - 1 - widx_w);   // tie -> min idx wins
            swc[buf][wave] = make_float4(cx, cy, cz, 0.0f);
        }
        __syncthreads();   // only LDS outstanding -> cheap lgkm drain

        // one parallel read burst: 4 keys + 4 coord packets, single drain
        unsigned long long k0 = swk[buf][0], k1 = swk[buf][1],
                           k2 = swk[buf][2], k3 = swk[buf][3];
        float4 c0 = swc[buf][0], c1 = swc[buf][1],
               c2 = swc[buf][2], c3 = swc[buf][3];

        // merge keys + select coords with the same comparisons (keys unique)
        unsigned long long ka = k0; float ax = c0.x, ay = c0.y, az = c0.z;
        if (k1 > ka) { ka = k1; ax = c1.x; ay = c1.y; az = c1.z; }
        unsigned long long kb = k2; float bx = c2.x, by = c2.y, bz = c2.z;
        if (k3 > kb) { kb = k3; bx = c3.x; by = c3.y; bz = c3.z; }
        if (kb > ka) { ka = kb; ax = bx; ay = by; az = bz; }

        int widx = N_PER - 1 - (int)(unsigned)(ka & 0xFFFu);
        lx = ax; ly = ay; lz = az;
        if (tid == 0) sloc[s] = widx;      // LDS, drained at next barrier
    }

    // dump sampled indices to global once (coalesced)
    __syncthreads();
    for (int i = tid; i < M_SAMP; i += TPB)
        sidx[cloud * M_SAMP + i] = sloc[i];
}

// ---------------------------------------------------------------------------
// Gather x rows: out[r][:] = x[g][:], float4-vectorized. 16384 rows x 128 f4.
// sidx holds LOCAL per-cloud indices; globalize with cloud offset r/M*N_PER.
// ---------------------------------------------------------------------------
__global__ __launch_bounds__(256) void gather_x_kernel(const float4* __restrict__ x4,
                                                       const int* __restrict__ sidx,
                                                       float4* __restrict__ out4) {
    int id = blockIdx.x * 256 + threadIdx.x;     // 0 .. 16384*128-1
    int r  = id >> 7;                            // row in output
    int c  = id & 127;                           // float4 column
    int g  = sidx[r] + (r >> 10 << 12);          // + (r/1024)*4096 global offset
    out4[id] = x4[(size_t)g * (D_FEAT / 4) + c];
}

// ---------------------------------------------------------------------------
// Gather pos (3 f32/row) and batch (as float). 16384 threads.
// ---------------------------------------------------------------------------
__global__ __launch_bounds__(256) void gather_pb_kernel(const float* __restrict__ pos,
                                                        const int* __restrict__ batch,
                                                        const int* __restrict__ sidx,
                                                        float* __restrict__ out_pos,
                                                        float* __restrict__ out_batch) {
    int r = blockIdx.x * 256 + threadIdx.x;      // 0 .. 16383
    int g = sidx[r] + (r >> 10 << 12);
    out_pos[r * 3 + 0] = pos[g * 3 + 0];
    out_pos[r * 3 + 1] = pos[g * 3 + 1];
    out_pos[r * 3 + 2] = pos[g * 3 + 2];
    out_batch[r] = (float)batch[g];
}

extern "C" void kernel_launch(void* const* d_in, const int* in_sizes, int n_in,
                              void* d_out, int out_size, void* d_ws, size_t ws_size,
                              hipStream_t stream) {
    const float* x     = (const float*)d_in[0];   // [65536,512] f32
    const float* pos   = (const float*)d_in[1];   // [65536,3]   f32
    const int*   batch = (const int*)d_in[2];     // [65536]     i32

    int* sidx = (int*)d_ws;                       // [16384] local sampled indices

    float* out   = (float*)d_out;
    float* out_x = out;                                            // 16384*512
    float* out_p = out + (size_t)B_CL * M_SAMP * D_FEAT;           // 16384*3
    float* out_b = out_p + (size_t)B_CL * M_SAMP * 3;              // 16384

    // 1) FPS: 16 blocks (one per cloud), 256 threads
    fps_kernel<<<B_CL, TPB, 0, stream>>>(pos, sidx);

    // 2) x gather: 16384 rows * 128 float4 / 256 threads = 8192 blocks
    gather_x_kernel<<<(B_CL * M_SAMP * (D_FEAT / 4)) / 256, 256, 0, stream>>>(
        (const float4*)x, sidx, (float4*)out_x);

    // 3) pos + batch gather: 16384 / 256 = 64 blocks
    gather_pb_kernel<<<(B_CL * M_SAMP) / 256, 256, 0, stream>>>(
        pos, batch, sidx, out_p, out_b);
}

// Round 5
// 786.659 us; speedup vs baseline: 1.0298x; 1.0298x over previous
//
#include <hip/hip_runtime.h>

// Problem constants (from reference): 16 clouds x 4096 pts, sample 1024, D=512
#define N_PER   4096
#define M_SAMP  1024
#define B_CL    16
#define D_FEAT  512
#define TPB     256
#define NWAVE   (TPB / 64)      // 4 waves
#define PPT     (N_PER / TPB)   // 16 points per thread
#define NPAIR   (PPT / 2)       // 8 packed pairs per thread

typedef float v2f __attribute__((ext_vector_type(2)));

// ---------------------------------------------------------------------------
// u32 DPP max combine (value-only wave reduce). Lanes not supplied by the
// pattern combine with themselves (old == own value -> no-op).
// ---------------------------------------------------------------------------
template <int CTRL>
__device__ __forceinline__ unsigned dpp_maxu(unsigned v) {
    unsigned o = (unsigned)__builtin_amdgcn_update_dpp((int)v, (int)v, CTRL, 0xF, 0xF, false);
    return (o > v) ? o : v;
}

// ---------------------------------------------------------------------------
// FPS: one workgroup per cloud, 256 threads, 1 wave/SIMD.
// Measured history: R1 LDS-spin +29% (reverted), R3 2-waves/SIMD +7%
// (reverted), R4 coord-ship via DIVERGENT spos read +14% (bank conflicts
// 57K->898K). This round keeps R4's post-barrier fusion (one LDS burst:
// keys+coords, no dependent spos round) but transports coords via a
// BROADCAST read spos[widx_w] (wave-uniform address -> 0 conflicts, no
// per-component readlanes).
//
// Exactness (identical to verified 549us R2 kernel):
//  - distance math contract(off), same op order -> bit-exact d2 chain
//  - value-only in-loop max via v_max3_f32; first-occurrence index by
//    descending equality scan (min j wins)
//  - wave reduce: 6-stage u32 DPP max on float bits (all dist >= 0)
//  - winner lane via readlane(63) -> ballot -> ctz (lane order == idx order)
//  - cross-wave merge via u64 keys (dist bits << 32 | (4095 - idx)):
//    max key == max dist, tie -> smaller global idx (jnp.argmax semantics);
//    coords selected by the same comparisons (keys unique -> exact).
// ---------------------------------------------------------------------------
__global__ __launch_bounds__(TPB)
__attribute__((amdgpu_waves_per_eu(1, 1)))
void fps_kernel(const float* __restrict__ pos, int* __restrict__ sidx) {
    __shared__ float4 spos[N_PER];                            // 64 KiB coord table
    __shared__ alignas(16) unsigned long long swk[2][NWAVE];  // wave keys (dbuf)
    __shared__ alignas(16) float4             swc[2][NWAVE];  // wave winner coords
    __shared__ int sloc[M_SAMP];                              // sampled local idx

    const int cloud = blockIdx.x;
    const int tid   = threadIdx.x;
    const float* posb = pos + (size_t)cloud * N_PER * 3;

    // preload my 16 points (12 aligned float4 from global), pack into v2f regs,
    // and stage the same points into spos (one-time)
    v2f px2[NPAIR], py2[NPAIR], pz2[NPAIR], dist2[NPAIR];
    const int base = tid * PPT;
    {
        float f[48];
        const float4* posb4 = (const float4*)posb + tid * 12;
#pragma unroll
        for (int v = 0; v < 12; ++v) {
            float4 t = posb4[v];
            f[4 * v + 0] = t.x; f[4 * v + 1] = t.y;
            f[4 * v + 2] = t.z; f[4 * v + 3] = t.w;
        }
#pragma unroll
        for (int p = 0; p < NPAIR; ++p) {
            px2[p] = (v2f){f[6 * p + 0], f[6 * p + 3]};
            py2[p] = (v2f){f[6 * p + 1], f[6 * p + 4]};
            pz2[p] = (v2f){f[6 * p + 2], f[6 * p + 5]};
            dist2[p] = (v2f){1e30f, 1e30f};
        }
#pragma unroll
        for (int j = 0; j < PPT; ++j)
            spos[base + j] = make_float4(f[3 * j], f[3 * j + 1], f[3 * j + 2], 0.0f);
    }

    float lx = posb[0], ly = posb[1], lz = posb[2];   // start point = local 0
    if (tid == 0) sloc[0] = 0;

    const int wave = tid >> 6;
    const int lane = tid & 63;
    __syncthreads();   // spos visible

    for (int s = 1; s < M_SAMP; ++s) {
        float bv = -1.0f;     // all dist >= 0, so always beaten
        v2f lxv = {lx, lx}, lyv = {ly, ly}, lzv = {lz, lz};
#pragma unroll
        for (int p = 0; p < NPAIR; ++p) {
#pragma clang fp contract(off)
            v2f dx = px2[p] - lxv;
            v2f dy = py2[p] - lyv;
            v2f dz = pz2[p] - lzv;
            v2f d2 = dx * dx + dy * dy + dz * dz;          // contract off: exact jnp order
            v2f dn = __builtin_elementwise_min(dist2[p], d2);
            dist2[p] = dn;
            // value-only running max: one v_max3_f32 per pair
            asm("v_max3_f32 %0, %1, %2, %3" : "=v"(bv) : "v"(bv), "v"(dn.x), "v"(dn.y));
        }

        // first-occurrence j among my 16 slots: descending overwrite -> min j
        // (independent of the DPP chain below; scheduler fills its bubbles)
        int bj = 0;
#pragma unroll
        for (int j = PPT - 1; j >= 0; --j) {
            float dj = (j & 1) ? dist2[j >> 1].y : dist2[j >> 1].x;
            bj = (dj == bv) ? j : bj;
        }

        // wave64 value max via u32 DPP (bv >= 0 -> float bits monotone)
        unsigned khi = __float_as_uint(bv);
        unsigned r = khi;
        r = dpp_maxu<0xB1>(r);     // quad_perm xor1
        r = dpp_maxu<0x4E>(r);     // quad_perm xor2
        r = dpp_maxu<0x141>(r);    // row_half_mirror
        r = dpp_maxu<0x140>(r);    // row_mirror
        r = dpp_maxu<0x142>(r);    // row_bcast15
        r = dpp_maxu<0x143>(r);    // row_bcast31  -> lane63 holds wave max

        unsigned smax = (unsigned)__builtin_amdgcn_readlane((int)r, 63);
        unsigned long long mask = __ballot(khi == smax);   // nonzero by construction
        int sl = __builtin_ctzll(mask);                    // first lane == lowest idx
        int widx_w = __builtin_amdgcn_readlane(base + bj, sl);  // wave winner (uniform)

        const int buf = s & 1;
        // key write issues first (independent), broadcast coord read overlaps it
        if (lane == 0)
            swk[buf][wave] = ((unsigned long long)smax << 32) |
                             (unsigned)(N_PER - 1 - widx_w);   // tie -> min idx wins
        float4 cw = spos[widx_w];          // BROADCAST read: 0 bank conflicts
        if (lane == 0)
            swc[buf][wave] = cw;
        __syncthreads();   // only LDS outstanding -> cheap lgkm drain

        // single pipelined burst: 2x b128 keys + 4x b128 coords, one drain
        const ulonglong2* kp = (const ulonglong2*)&swk[buf][0];
        ulonglong2 kA = kp[0], kB = kp[1];
        float4 c0 = swc[buf][0], c1 = swc[buf][1],
               c2 = swc[buf][2], c3 = swc[buf][3];

        // merge keys + select coords with the same comparisons (keys unique)
        unsigned long long ka = kA.x; float ax = c0.x, ay = c0.y, az = c0.z;
        if (kA.y > ka) { ka = kA.y; ax = c1.x; ay = c1.y; az = c1.z; }
        unsigned long long kb = kB.x; float bx = c2.x, by = c2.y, bz = c2.z;
        if (kB.y > kb) { kb = kB.y; bx = c3.x; by = c3.y; bz = c3.z; }
        if (kb > ka) { ka = kb; ax = bx; ay = by; az = bz; }

        lx = ax; ly = ay; lz = az;
        if (tid == 0)
            sloc[s] = N_PER - 1 - (int)(unsigned)(ka & 0xFFFu);  // LDS, drained later
    }

    // dump sampled indices to global once (coalesced)
    __syncthreads();
    for (int i = tid; i < M_SAMP; i += TPB)
        sidx[cloud * M_SAMP + i] = sloc[i];
}

// ---------------------------------------------------------------------------
// Gather x rows: out[r][:] = x[g][:], float4-vectorized. 16384 rows x 128 f4.
// sidx holds LOCAL per-cloud indices; globalize with cloud offset r/M*N_PER.
// ---------------------------------------------------------------------------
__global__ __launch_bounds__(256) void gather_x_kernel(const float4* __restrict__ x4,
                                                       const int* __restrict__ sidx,
                                                       float4* __restrict__ out4) {
    int id = blockIdx.x * 256 + threadIdx.x;     // 0 .. 16384*128-1
    int r  = id >> 7;                            // row in output
    int c  = id & 127;                           // float4 column
    int g  = sidx[r] + (r >> 10 << 12);          // + (r/1024)*4096 global offset
    out4[id] = x4[(size_t)g * (D_FEAT / 4) + c];
}

// ---------------------------------------------------------------------------
// Gather pos (3 f32/row) and batch (as float). 16384 threads.
// ---------------------------------------------------------------------------
__global__ __launch_bounds__(256) void gather_pb_kernel(const float* __restrict__ pos,
                                                        const int* __restrict__ batch,
                                                        const int* __restrict__ sidx,
                                                        float* __restrict__ out_pos,
                                                        float* __restrict__ out_batch) {
    int r = blockIdx.x * 256 + threadIdx.x;      // 0 .. 16383
    int g = sidx[r] + (r >> 10 << 12);
    out_pos[r * 3 + 0] = pos[g * 3 + 0];
    out_pos[r * 3 + 1] = pos[g * 3 + 1];
    out_pos[r * 3 + 2] = pos[g * 3 + 2];
    out_batch[r] = (float)batch[g];
}

extern "C" void kernel_launch(void* const* d_in, const int* in_sizes, int n_in,
                              void* d_out, int out_size, void* d_ws, size_t ws_size,
                              hipStream_t stream) {
    const float* x     = (const float*)d_in[0];   // [65536,512] f32
    const float* pos   = (const float*)d_in[1];   // [65536,3]   f32
    const int*   batch = (const int*)d_in[2];     // [65536]     i32

    int* sidx = (int*)d_ws;                       // [16384] local sampled indices

    float* out   = (float*)d_out;
    float* out_x = out;                                            // 16384*512
    float* out_p = out + (size_t)B_CL * M_SAMP * D_FEAT;           // 16384*3
    float* out_b = out_p + (size_t)B_CL * M_SAMP * 3;              // 16384

    // 1) FPS: 16 blocks (one per cloud), 256 threads
    fps_kernel<<<B_CL, TPB, 0, stream>>>(pos, sidx);

    // 2) x gather: 16384 rows * 128 float4 / 256 threads = 8192 blocks
    gather_x_kernel<<<(B_CL * M_SAMP * (D_FEAT / 4)) / 256, 256, 0, stream>>>(
        (const float4*)x, sidx, (float4*)out_x);

    // 3) pos + batch gather: 16384 / 256 = 64 blocks
    gather_pb_kernel<<<(B_CL * M_SAMP) / 256, 256, 0, stream>>>(
        pos, batch, sidx, out_p, out_b);
}